// Round 7
// baseline (9885.306 us; speedup 1.0000x reference)
//
#include <hip/hip_runtime.h>

typedef unsigned short ushort_t;
typedef unsigned long long u64_t;
typedef float  f32x4  __attribute__((ext_vector_type(4)));
typedef __bf16 bf16x8 __attribute__((ext_vector_type(8)));

// Problem sizes (fixed): B=64, S=512, D=1024, H=1024, 4H=4096
#define NB   64
#define NS   512
#define ND   1024
#define NH   1024
#define NG   4096   // 4*H

// ---------- helpers ----------
__device__ __forceinline__ ushort_t f2bf(float f) {
  unsigned u = __float_as_uint(f);
  u += 0x7FFFu + ((u >> 16) & 1u);   // round-to-nearest-even
  return (ushort_t)(u >> 16);
}
__device__ __forceinline__ float bf2f(ushort_t u) {
  return __uint_as_float(((unsigned)u) << 16);
}
__device__ __forceinline__ float sigmoid_f(float x) {
  return 1.0f / (1.0f + __expf(-x));
}
__device__ __forceinline__ float tanh_f(float x) {
  return 1.0f - 2.0f / (__expf(2.0f * x) + 1.0f);
}

// ---------- prep: fp32 -> bf16 conversions ----------
__global__ __launch_bounds__(256) void cvt_x_kernel(const float4* __restrict__ x,
                                                    ushort_t* __restrict__ xb) {
  int i = blockIdx.x * 256 + threadIdx.x;
  float4 v = x[i];
  ushort4 o;
  o.x = f2bf(v.x); o.y = f2bf(v.y); o.z = f2bf(v.z); o.w = f2bf(v.w);
  *(ushort4*)(xb + (size_t)i * 4) = o;
}

__global__ __launch_bounds__(256) void cvt_w_kernel(const float4* __restrict__ W,
                                                    ushort_t* __restrict__ Wx,
                                                    ushort_t* __restrict__ Wh) {
  int i = blockIdx.x * 256 + threadIdx.x;
  float4 v = W[i];
  int e = i * 4;
  int n = e >> 11;        // row of W  (2048 cols)
  int c = e & 2047;       // col of W
  ushort4 o;
  o.x = f2bf(v.x); o.y = f2bf(v.y); o.z = f2bf(v.z); o.w = f2bf(v.w);
  ushort_t* dst = (c < ND) ? (Wx + (size_t)n * ND + c)
                           : (Wh + (size_t)n * NH + (c - ND));
  *(ushort4*)dst = o;
}

// ---------- pre-GEMM: PG[t][b][n] = x @ Wx^T + bias  (bf16 out) ----------
__global__ __launch_bounds__(256) void pregemm_kernel(
    const ushort_t* __restrict__ xb, const ushort_t* __restrict__ Wx,
    const float* __restrict__ bias, ushort_t* __restrict__ PG) {
  int bid  = blockIdx.x;
  int mblk = bid >> 5;        // 256 m-blocks
  int nblk = bid & 31;        // 32 n-blocks
  int tid  = threadIdx.x;
  int lane = tid & 63, w = tid >> 6;
  int l15  = lane & 15, q = lane >> 4;
  int row0 = mblk * 128 + (w >> 1) * 64;
  int col0 = nblk * 128 + (w & 1) * 64;
  const ushort_t* aBase = xb + (size_t)(row0 + l15) * ND + q * 8;
  const ushort_t* bBase = Wx + (size_t)(col0 + l15) * ND + q * 8;

  f32x4 acc[4][4] = {};
#pragma unroll 2
  for (int k0 = 0; k0 < ND; k0 += 32) {
    bf16x8 a[4], b[4];
#pragma unroll
    for (int mi = 0; mi < 4; ++mi)
      a[mi] = *reinterpret_cast<const bf16x8*>(aBase + (size_t)mi * 16 * ND + k0);
#pragma unroll
    for (int ni = 0; ni < 4; ++ni)
      b[ni] = *reinterpret_cast<const bf16x8*>(bBase + (size_t)ni * 16 * ND + k0);
#pragma unroll
    for (int mi = 0; mi < 4; ++mi)
#pragma unroll
      for (int ni = 0; ni < 4; ++ni)
        acc[mi][ni] = __builtin_amdgcn_mfma_f32_16x16x32_bf16(a[mi], b[ni], acc[mi][ni], 0, 0, 0);
  }
#pragma unroll
  for (int ni = 0; ni < 4; ++ni) {
    int n = col0 + ni * 16 + l15;
    float bv = bias[n];
#pragma unroll
    for (int mi = 0; mi < 4; ++mi) {
#pragma unroll
      for (int r = 0; r < 4; ++r) {
        int m  = row0 + mi * 16 + q * 4 + r;
        int bb = m >> 9;          // batch
        int t  = m & 511;         // time
        PG[((size_t)t * NB + bb) * NG + n] = f2bf(acc[mi][ni][r] + bv);
      }
    }
  }
}

// ---------- recurrent: barrier-FREE tagged dataflow ----------
// 4 independent machines of 16 blocks (machine = bid>>4 owns batches
// [mach*16, +16); slot = bid&15 owns j-cols [slot*64, +64), all 4 gates).
// h elements are u32 = {step_tag:16 | bf16:16} in a per-machine double
// buffer at IC. NO flags, NO barrier, NO fences, NO store-drain:
//   producer: after the cell, each thread fire-and-forgets ONE tagged u32
//             agent-scope store (sc0 sc1 -> IC, L2 never dirty).
//   consumer: staging IS the sync -- load the machine's 64 KB h image as
//             u64 chunks and re-poll until every chunk's two tags == t
//             (8 loads in flight concurrently; retries pipeline).
// Critical path/step = store->IC (~1/2 RTT) + poll-observe (~1 RTT) +
// compute. No rendezvous: a block proceeds the moment ITS data arrives.
// Overwrite safety (R=2 buffers): to write h_{t+2} into buf[t&1] a block
// must first observe ALL tags t+1, which requires every block to have
// finished staging step t. Tag seen by a step-t stager is {t-2, t}: poll
// for == t. Tags init: memset zeros = tag 0 = valid h_0. Guard-bounded
// polls -> any protocol failure is a loud passed:false, never a hang.
__global__ __launch_bounds__(1024) void lstm_rec_kernel(
    const ushort_t* __restrict__ PG, const ushort_t* __restrict__ Wh,
    unsigned* hbuf, float* __restrict__ out) {
  __shared__ ushort_t lds_h[16 * 1024];     // 32768 B, batch-major, XOR-swizzled
  __shared__ float lds_g[4][16][66];        // 16896 B  (total ~49.7 KB)

  int bid  = blockIdx.x;
  int mach = bid >> 4;                 // 0..3  machine (16 batches)
  int slot = bid & 15;                 // 0..15 j-slot (64 columns)
  int tid  = threadIdx.x;
  int lane = tid & 63, w = tid >> 6;
  int g = w & 3, jb = w >> 2;          // wave -> (gate, 16-col j-block)
  int l15 = lane & 15, q = lane >> 4;
  int mb = tid >> 6, jc = tid & 63;    // cell phase: (batch, j-col) per thread

  // machine-local tagged h double buffers: 16 x 1024 u32 = 64 KB each
  unsigned* hm = hbuf + (size_t)mach * 2 * 16384;

  // B operand (Wh) from global: L2-resident (L2 is never invalidated)
  const ushort_t* bB =
      Wh + (size_t)(g * NH + slot * 64 + jb * 16 + l15) * NH + q * 8;

  // A-fragment LDS geometry: row = batch = l15, swizzle byte ^= (row&7)<<4
  int swA = (l15 & 7) << 4;
  const char* aRow = (const char*)lds_h + l15 * 2048;

  float c_reg = 0.f;                   // c lives in a register for all 512 steps

  int bglob = mach * 16 + mb;          // global batch of this thread's cell elem
  int jglob = slot * 64 + jc;          // global j-column

  // PG prefetch for t = 0 (nontemporal: don't evict Wh from L2)
  ushort_t pg0, pg1, pg2, pg3;
  {
    const ushort_t* pp = PG + (size_t)bglob * NG + jglob;
    pg0 = __builtin_nontemporal_load(pp);
    pg1 = __builtin_nontemporal_load(pp + NH);
    pg2 = __builtin_nontemporal_load(pp + 2 * NH);
    pg3 = __builtin_nontemporal_load(pp + 3 * NH);
  }

  for (int t = 0; t < NS; ++t) {
    // ---- stage machine's h_t: poll tagged u64 chunks until tags == t,
    // then strip tags and write bf16 pairs into swizzled LDS.
    {
      const u64_t* hb64 = (const u64_t*)(hm + (t & 1) * 16384);
      u64_t v[8];
      unsigned tg = (unsigned)t;
      int guard = 0;
      bool ok = false;
      while (!ok) {
#pragma unroll
        for (int it = 0; it < 8; ++it)
          v[it] = __hip_atomic_load(hb64 + it * 1024 + tid,
                                    __ATOMIC_RELAXED, __HIP_MEMORY_SCOPE_AGENT);
        ok = true;
#pragma unroll
        for (int it = 0; it < 8; ++it) {
          unsigned t0 = ((unsigned)(v[it] >> 16)) & 0xffffu;
          unsigned t1 = (unsigned)(v[it] >> 48);
          ok = ok && (t0 == tg) && (t1 == tg);
        }
        if (++guard > (1 << 12)) break;   // loud fail, never hang
      }
#pragma unroll
      for (int it = 0; it < 8; ++it) {
        int idx = 2 * (it * 1024 + tid);   // u32 element index (16 rows x 1024)
        int row = idx >> 10;
        int j0  = idx & 1023;              // even
        unsigned val = ((unsigned)v[it] & 0xffffu) |
                       ((((unsigned)(v[it] >> 32)) & 0xffffu) << 16);
        *(unsigned*)((char*)lds_h + row * 2048 + ((j0 * 2) ^ ((row & 7) << 4))) = val;
      }
    }
    __syncthreads();

    // ---- GEMM: 16(batch)x16(j) tile per wave, A from swizzled LDS, B from L2
    f32x4 acc = {};
#pragma unroll 8
    for (int k0 = 0; k0 < NH; k0 += 32) {
      bf16x8 av = *(const bf16x8*)(aRow + ((16 * q + 2 * k0) ^ swA));
      bf16x8 bv = *reinterpret_cast<const bf16x8*>(bB + k0);
      acc = __builtin_amdgcn_mfma_f32_16x16x32_bf16(av, bv, acc, 0, 0, 0);
    }
    // C/D layout: col(l15) = B-row = j-within-16, row(q*4+r) = A-row = batch
#pragma unroll
    for (int r = 0; r < 4; ++r)
      lds_g[g][q * 4 + r][jb * 16 + l15] = acc[r];
    __syncthreads();

    // ---- cell: 1 (mb, jc) element per thread
    float gi = lds_g[0][mb][jc] + bf2f(pg0);
    float gf = lds_g[1][mb][jc] + bf2f(pg1);
    float go = lds_g[2][mb][jc] + bf2f(pg2);
    float gg = lds_g[3][mb][jc] + bf2f(pg3);
    float cn = sigmoid_f(gf) * c_reg + sigmoid_f(gi) * tanh_f(gg);
    float hv = sigmoid_f(go) * tanh_f(cn);
    c_reg = cn;

    if (t == NS - 1) {
      out[((size_t)bglob * NS + t) * NH + jglob] = hv;
      out[(size_t)NB * NS * NH + (size_t)bglob * NH + jglob] = hv;                    // final h
      out[(size_t)NB * NS * NH + (size_t)NB * NH + (size_t)bglob * NH + jglob] = cn;  // final c
    } else {
      // publish h_{t+1} IMMEDIATELY: one tagged u32, fire-and-forget
      // (write-through to IC; consumers validate via the embedded tag)
      unsigned pub = (unsigned)f2bf(hv) | (((unsigned)(t + 1)) << 16);
      unsigned* hn = hm + ((t + 1) & 1) * 16384;
      __hip_atomic_store(hn + mb * 1024 + jglob, pub,
                         __ATOMIC_RELAXED, __HIP_MEMORY_SCOPE_AGENT);
      // off-critical-path: out store (nt) + PG prefetch for t+1
      __builtin_nontemporal_store(hv, &out[((size_t)bglob * NS + t) * NH + jglob]);
      const ushort_t* pn = PG + ((size_t)(t + 1) * NB + bglob) * NG + jglob;
      pg0 = __builtin_nontemporal_load(pn);
      pg1 = __builtin_nontemporal_load(pn + NH);
      pg2 = __builtin_nontemporal_load(pn + 2 * NH);
      pg3 = __builtin_nontemporal_load(pn + 3 * NH);
    }
  }
}

// ---------- launch ----------
extern "C" void kernel_launch(void* const* d_in, const int* in_sizes, int n_in,
                              void* d_out, int out_size, void* d_ws, size_t ws_size,
                              hipStream_t stream) {
  const float* x    = (const float*)d_in[0];
  const float* W    = (const float*)d_in[1];
  const float* bias = (const float*)d_in[2];
  float* out = (float*)d_out;

  const size_t off_hbuf = 0;                         // 4 mach * 2 * 64 KB = 524288
  const size_t off_Wx   = 524288;                    // 8388608
  const size_t off_Wh   = off_Wx + 8388608;          // 8388608
  const size_t off_xb   = off_Wh + 8388608;          // 67108864
  const size_t off_PG   = off_xb + 67108864;         // 268435456
  const size_t need     = off_PG + 268435456;        // ~336.6 MB
  if (ws_size < need) return;

  char* ws = (char*)d_ws;
  unsigned* hbuf = (unsigned*)(ws + off_hbuf);
  ushort_t* Wx   = (ushort_t*)(ws + off_Wx);
  ushort_t* Wh   = (ushort_t*)(ws + off_Wh);
  ushort_t* xb   = (ushort_t*)(ws + off_xb);
  ushort_t* PG   = (ushort_t*)(ws + off_PG);

  hipMemsetAsync(ws, 0, 524288, stream);   // h_0 = 0 with tag 0 (valid)

  cvt_x_kernel<<<32768, 256, 0, stream>>>((const float4*)x, xb);
  cvt_w_kernel<<<8192, 256, 0, stream>>>((const float4*)W, Wx, Wh);
  pregemm_kernel<<<8192, 256, 0, stream>>>(xb, Wx, bias, PG);

  // cooperative launch kept only for the co-residency guarantee (64 blocks)
  void* args[] = { (void*)&PG, (void*)&Wh, (void*)&hbuf, (void*)&out };
  hipLaunchCooperativeKernel((void*)lstm_rec_kernel, dim3(64), dim3(1024),
                             args, 0, stream);
}